// Round 6
// baseline (211.315 us; speedup 1.0000x reference)
//
#include <hip/hip_runtime.h>
#include <math.h>
#include <stdint.h>

// ---------------- model constants ----------------
#define BATCH 65536
#define TB 128           // 4 waves x 32 rows (2 m-tiles), each wave independent

typedef _Float16 half8 __attribute__((ext_vector_type(8)));
typedef float   floatx4 __attribute__((ext_vector_type(4)));

// per-wave LDS strides (halves)
#define SH 68            // hH: 64 cols + 4 pad  (34 dwords ≡ 2 mod 32: conflict-free)
#define SM 130           // hM: 129 cols + 1     (65 dwords ≡ 1 mod 32: conflict-free)
#define HM_SLICE (32*SM + 64)   // +64 halves zeroed tail pad (overrun reads)

// packed-weight geometry (f16), FRAGMENT-ORDERED:
//   element (ks, nt, lane, j) at ((ks*NT + nt)*512) + lane*8 + j
//   maps to B[k = ks*32 + (lane>>4)*8 + j][n = nt*16 + (lane&15)]
// -> a wave's B-frag load is base + lane*16B: one coalesced 1KB transaction.
#define WIN 2048          // stage1: 1 kstep x 4 ntiles x 512
#define KSA 18            // a: 16 spline ksteps (512 k) + 2 silu (64)
#define KSB 39            // b: 34 spline ksteps (1088 k, 129 real) + 5 silu (160, 129 real)
#define WA (KSA*9*512)    // 82944
#define WB (KSB*4*512)    // 79872
#define WTOT (WIN + 2*(WA+WB))   // 327680 halfs = 655360 B of d_ws

// ---------------------------------------------------------------------------
// setup: pack all weights f16 in fragment order (identical to r5).
// ---------------------------------------------------------------------------
__global__ void setup_weights(
    const float* __restrict__ W_in,
    const float* __restrict__ c0a, const float* __restrict__ sb0a, const float* __restrict__ ss0a,
    const float* __restrict__ c0b, const float* __restrict__ sb0b, const float* __restrict__ ss0b,
    const float* __restrict__ c1a, const float* __restrict__ sb1a, const float* __restrict__ ss1a,
    const float* __restrict__ c1b, const float* __restrict__ sb1b, const float* __restrict__ ss1b,
    _Float16* __restrict__ wt) {
  int idx = blockIdx.x * 256 + threadIdx.x;
  if (idx >= WTOT) return;
  float v = 0.0f;
  if (idx < WIN) {                        // W_in: [32][64] -> frag order, 4 ntiles
    int nt = idx >> 9; int r = idx & 511; int l = r >> 3; int j = r & 7;
    int n = nt*16 + (l & 15);
    int k = (l >> 4)*8 + j;
    v = W_in[k*64 + n];
  } else {
    int e2   = idx - WIN;
    int pair = (e2 >= WA + WB) ? 1 : 0;
    int e    = e2 - pair * (WA + WB);
    if (e < WA) {                         // a-type: I=64, O=129 (9 ntiles)
      const float* coef = pair ? c1a : c0a;
      const float* sb   = pair ? sb1a : sb0a;
      const float* ss   = pair ? ss1a : ss0a;
      int ks = e / 4608; int r = e - ks*4608;
      int nt = r >> 9;   int q = r & 511;
      int l  = q >> 3;   int j = q & 7;
      int n  = nt*16 + (l & 15);
      int k  = ks*32 + (l >> 4)*8 + j;
      if (n < 129) {
        if (k < 512) { int i = k >> 3, p = k & 7; v = ss[i*129+n] * coef[(i*129+n)*8 + p]; }
        else         { int i = k - 512;           v = sb[i*129+n]; }     // i < 64
      }
    } else {                              // b-type: I=129, O=64 (4 ntiles)
      const float* coef = pair ? c1b : c0b;
      const float* sb   = pair ? sb1b : sb0b;
      const float* ss   = pair ? ss1b : ss0b;
      int eb = e - WA;
      int ks = eb >> 11; int r = eb & 2047;
      int nt = r >> 9;   int q = r & 511;
      int l  = q >> 3;   int j = q & 7;
      int n  = nt*16 + (l & 15);
      int k  = ks*32 + (l >> 4)*8 + j;
      if (k < 1088) { int i = k >> 3, p = k & 7; if (i < 129) v = ss[i*64+n] * coef[(i*64+n)*8 + p]; }
      else          { int i = k - 1088;          if (i < 129) v = sb[i*64+n]; }
    }
  }
  wt[idx] = (_Float16)v;
}

// ---------------------------------------------------------------------------
// feat8: 8 B-spline basis values of x as a ready A-fragment (half8).
// Funnel-shift placement (validated r5, absmax 0.0059).
// ---------------------------------------------------------------------------
__device__ __forceinline__ half8 feat8(float x) {
  float s  = (x + 2.2f) * 2.5f;
  float mf = floorf(s);
  int   m  = (int)mf;
  float u  = s - mf;
  float t  = 1.0f - u;
  float u2 = u*u;
  float w0 = t*t*t * (1.0f/6.0f);
  float w3 = u2*u * (1.0f/6.0f);
  float w1 = fmaf(u2, fmaf(0.5f, u, -1.0f), 2.0f/3.0f);   // (3u^3-6u^2+4)/6
  float w2 = 1.0f - w0 - w1 - w3;                          // partition of unity
  union { _Float16 h[4]; uint64_t u; } P;
  P.h[0] = (_Float16)w0; P.h[1] = (_Float16)w1;
  P.h[2] = (_Float16)w2; P.h[3] = (_Float16)w3;
  uint64_t w01 = (m >= 0 && m <= 10) ? P.u : 0ull;
  int sh = (m - 3) * 16;                                   // bits; [-48,112] valid
  uint64_t q0 = (sh >= 0) ? ((sh < 64) ? (w01 << sh) : 0ull) : (w01 >> (-sh));
  uint64_t q1 = (sh >= 64) ? (w01 << (sh - 64))
                           : ((sh > 0) ? (w01 >> (64 - sh)) : 0ull);
  union { uint64_t q[2]; half8 h; } R;
  R.q[0] = q0; R.q[1] = q1;
  return R.h;
}

// ---------------------------------------------------------------------------
// one KAN layer, per-wave: 32 rows = 2 m-tiles sharing every B-fragment
// (halves per-CU L1 weight traffic vs r5). A-frags built in registers.
// ---------------------------------------------------------------------------
template<int KSPL, int KSIL, int NT, int SIN, int O, int SOUT>
__device__ __forceinline__ void kan_layer(
    const _Float16* __restrict__ hinw, _Float16* __restrict__ houtw,
    const _Float16* __restrict__ wt, const float* __restrict__ bias, int lane) {
  const int ln = lane & 15;
  const int kq = lane >> 4;
  floatx4 acc0[NT], acc1[NT];
  #pragma unroll
  for (int j = 0; j < NT; ++j) {
    acc0[j] = (floatx4){0.f, 0.f, 0.f, 0.f};
    acc1[j] = (floatx4){0.f, 0.f, 0.f, 0.f};
  }

  // ---- spline k-steps: input i = ks*4 + kq, rows ln and 16+ln ----
  #pragma unroll 2
  for (int ks = 0; ks < KSPL; ++ks) {
    float xv0 = (float)hinw[ ln      *SIN + ks*4 + kq];
    float xv1 = (float)hinw[(16 + ln)*SIN + ks*4 + kq];
    half8 A0 = feat8(xv0);
    half8 A1 = feat8(xv1);
    #pragma unroll
    for (int j = 0; j < NT; ++j) {
      half8 B = *(const half8*)&wt[((ks*NT + j) << 9) + lane*8];
      acc0[j] = __builtin_amdgcn_mfma_f32_16x16x32_f16(A0, B, acc0[j], 0, 0, 0);
      acc1[j] = __builtin_amdgcn_mfma_f32_16x16x32_f16(A1, B, acc1[j], 0, 0, 0);
    }
  }

  // ---- silu k-steps: slots = silu(h[row][sk*32+kq*8 .. +7]) ----
  #pragma unroll 2
  for (int sk = 0; sk < KSIL; ++sk) {
    half8 h0 = *(const half8*)&hinw[ ln      *SIN + sk*32 + kq*8];
    half8 h1 = *(const half8*)&hinw[(16 + ln)*SIN + sk*32 + kq*8];
    half8 A0, A1;
    #pragma unroll
    for (int e = 0; e < 8; ++e) {
      float x0 = (float)h0[e], x1 = (float)h1[e];
      A0[e] = (_Float16)(x0 / (1.0f + __expf(-x0)));
      A1[e] = (_Float16)(x1 / (1.0f + __expf(-x1)));
    }
    #pragma unroll
    for (int j = 0; j < NT; ++j) {
      half8 B = *(const half8*)&wt[(((KSPL + sk)*NT + j) << 9) + lane*8];
      acc0[j] = __builtin_amdgcn_mfma_f32_16x16x32_f16(A0, B, acc0[j], 0, 0, 0);
      acc1[j] = __builtin_amdgcn_mfma_f32_16x16x32_f16(A1, B, acc1[j], 0, 0, 0);
    }
  }

  // ---- epilogue: C/D col=lane&15, row=kq*4+r (m89-verified) ----
  #pragma unroll
  for (int j = 0; j < NT; ++j) {
    int col = j*16 + ln;
    if (col < O) {
      float bv = bias[col];
      #pragma unroll
      for (int r = 0; r < 4; ++r) {
        houtw[(      kq*4 + r)*SOUT + col] = (_Float16)(acc0[j][r] + bv);
        houtw[(16 + kq*4 + r)*SOUT + col] = (_Float16)(acc1[j][r] + bv);
      }
    }
  }
}

// ---------------------------------------------------------------------------
// fused forward, zero __syncthreads, register A-frags, 2 m-tiles/wave.
// LDS = 4*(32*68 + 32*130+64)*2B = 51200 B -> 2 blocks/CU (grid 512 = exact).
// ---------------------------------------------------------------------------
extern "C" __global__ void __launch_bounds__(256, 2)
kan_forward(const float* __restrict__ x, const float* __restrict__ b_in,
            const float* __restrict__ W_out, const _Float16* __restrict__ wt,
            const float* __restrict__ bias0a, const float* __restrict__ bias0b,
            const float* __restrict__ bias1a, const float* __restrict__ bias1b,
            float* __restrict__ out) {
  __shared__ _Float16 hM[4][HM_SLICE];
  __shared__ _Float16 hH[4][32*SH];
  const int t    = threadIdx.x;
  const int wv   = t >> 6;
  const int lane = t & 63;
  const int ln   = lane & 15;
  const int kq   = lane >> 4;
  _Float16* hMw = hM[wv];
  _Float16* hHw = hH[wv];
  const int rbase = blockIdx.x * TB + wv * 32;

  // zero hM spots that padded spline/silu reads can touch with garbage:
  // col 129 of each row (never written; read by layer-b silu) and tail pad.
  hMw[32*SM + lane] = (_Float16)0.0f;
  if (lane < 32) hMw[lane*SM + 129] = (_Float16)0.0f;

  // stage 1: hH = relu(x @ W_in + b_in). A-frags straight from global x.
  {
    const float* xr0 = &x[(rbase + ln     )*32 + kq*8];
    const float* xr1 = &x[(rbase + 16 + ln)*32 + kq*8];
    float4 a0 = *(const float4*)&xr0[0];
    float4 a1 = *(const float4*)&xr0[4];
    float4 b0 = *(const float4*)&xr1[0];
    float4 b1 = *(const float4*)&xr1[4];
    half8 A0 = { (_Float16)a0.x, (_Float16)a0.y, (_Float16)a0.z, (_Float16)a0.w,
                 (_Float16)a1.x, (_Float16)a1.y, (_Float16)a1.z, (_Float16)a1.w };
    half8 A1 = { (_Float16)b0.x, (_Float16)b0.y, (_Float16)b0.z, (_Float16)b0.w,
                 (_Float16)b1.x, (_Float16)b1.y, (_Float16)b1.z, (_Float16)b1.w };
    #pragma unroll
    for (int nt = 0; nt < 4; ++nt) {
      floatx4 z = (floatx4){0.f, 0.f, 0.f, 0.f};
      half8 B = *(const half8*)&wt[(nt << 9) + lane*8];
      floatx4 c0 = __builtin_amdgcn_mfma_f32_16x16x32_f16(A0, B, z, 0, 0, 0);
      floatx4 c1 = __builtin_amdgcn_mfma_f32_16x16x32_f16(A1, B, z, 0, 0, 0);
      int col = nt*16 + ln;
      float bv = b_in[col];
      #pragma unroll
      for (int r = 0; r < 4; ++r) {
        hHw[(      kq*4 + r)*SH + col] = (_Float16)fmaxf(c0[r] + bv, 0.0f);
        hHw[(16 + kq*4 + r)*SH + col] = (_Float16)fmaxf(c1[r] + bv, 0.0f);
      }
    }
  }

  // two KAN pairs via rep-loop (halves code size / I-cache footprint)
  const _Float16* wp = wt + WIN;
  #pragma unroll 1
  for (int rep = 0; rep < 2; ++rep) {
    const float* ba = rep ? bias1a : bias0a;
    const float* bb = rep ? bias1b : bias0b;
    kan_layer<16,2,9,SH,129,SM>(hHw, hMw, wp,      ba, lane);
    kan_layer<34,5,4,SM, 64,SH>(hMw, hHw, wp + WA, bb, lane);
    wp += WA + WB;
  }

  // final: out = sigmoid(hH @ W_out); two col-halves reduced by shuffle
  {
    int row = lane & 31;
    int kh  = lane >> 5;
    float s = 0.0f;
    #pragma unroll
    for (int j = 0; j < 32; ++j)
      s = fmaf((float)hHw[row*SH + kh*32 + j], W_out[kh*32 + j], s);
    s += __shfl_down(s, 32);
    if (lane < 32) out[rbase + row] = 1.0f / (1.0f + __expf(-s));
  }
}

// ---------------------------------------------------------------------------
extern "C" void kernel_launch(void* const* d_in, const int* in_sizes, int n_in,
                              void* d_out, int out_size, void* d_ws, size_t ws_size,
                              hipStream_t stream) {
  const float* x     = (const float*)d_in[0];
  const float* W_in  = (const float*)d_in[1];
  const float* b_in  = (const float*)d_in[2];
  const float* W_out = (const float*)d_in[3];
  const float* c0a = (const float*)d_in[4];  const float* sb0a = (const float*)d_in[5];
  const float* ss0a= (const float*)d_in[6];  const float* bias0a=(const float*)d_in[7];
  const float* c0b = (const float*)d_in[8];  const float* sb0b = (const float*)d_in[9];
  const float* ss0b= (const float*)d_in[10]; const float* bias0b=(const float*)d_in[11];
  const float* c1a = (const float*)d_in[12]; const float* sb1a = (const float*)d_in[13];
  const float* ss1a= (const float*)d_in[14]; const float* bias1a=(const float*)d_in[15];
  const float* c1b = (const float*)d_in[16]; const float* sb1b = (const float*)d_in[17];
  const float* ss1b= (const float*)d_in[18]; const float* bias1b=(const float*)d_in[19];
  float*    out = (float*)d_out;
  _Float16* wt  = (_Float16*)d_ws;       // 655,360 B scratch, repacked every call

  setup_weights<<<(WTOT + 255)/256, 256, 0, stream>>>(
      W_in, c0a, sb0a, ss0a, c0b, sb0b, ss0b,
      c1a, sb1a, ss1a, c1b, sb1b, ss1b, wt);

  kan_forward<<<BATCH/TB, 256, 0, stream>>>(
      x, b_in, W_out, wt, bias0a, bias0b, bias1a, bias1b, out);
}

// Round 8
// 188.002 us; speedup vs baseline: 1.1240x; 1.1240x over previous
//
#include <hip/hip_runtime.h>
#include <math.h>
#include <stdint.h>

// ---------------- model constants ----------------
#define BATCH 65536
#define TB 64            // 4 waves x 16 rows, each wave independent (r5 structure)

typedef __fp16   fp16x2 __attribute__((ext_vector_type(2)));   // cvt_pkrtz result type
typedef _Float16 half8  __attribute__((ext_vector_type(8)));
typedef float   floatx4 __attribute__((ext_vector_type(4)));

// per-wave LDS strides (halves)
#define SH 68            // hH: 64 cols + 4 pad  (34 dwords ≡ 2 mod 32: conflict-free)
#define SM 130           // hM: 129 cols + 1     (65 dwords ≡ 1 mod 32: conflict-free)
#define HM_SLICE (16*SM + 64)   // +64 halves zeroed tail pad (overrun reads)

// packed-weight geometry (f16), FRAGMENT-ORDERED (identical to r5):
//   element (ks, nt, lane, j) at ((ks*NT + nt)*512) + lane*8 + j
//   maps to B[k = ks*32 + (lane>>4)*8 + j][n = nt*16 + (lane&15)]
#define WIN 2048          // stage1: 1 kstep x 4 ntiles x 512
#define KSA 18            // a: 16 spline ksteps (512 k) + 2 silu (64)
#define KSB 39            // b: 34 spline ksteps (1088 k, 129 real) + 5 silu (160, 129 real)
#define WA (KSA*9*512)    // 82944
#define WB (KSB*4*512)    // 79872
#define WTOT (WIN + 2*(WA+WB))   // 327680 halfs = 655360 B of d_ws

// ---------------------------------------------------------------------------
// setup: pack all weights f16 in fragment order (identical to r5).
// ---------------------------------------------------------------------------
__global__ void setup_weights(
    const float* __restrict__ W_in,
    const float* __restrict__ c0a, const float* __restrict__ sb0a, const float* __restrict__ ss0a,
    const float* __restrict__ c0b, const float* __restrict__ sb0b, const float* __restrict__ ss0b,
    const float* __restrict__ c1a, const float* __restrict__ sb1a, const float* __restrict__ ss1a,
    const float* __restrict__ c1b, const float* __restrict__ sb1b, const float* __restrict__ ss1b,
    _Float16* __restrict__ wt) {
  int idx = blockIdx.x * 256 + threadIdx.x;
  if (idx >= WTOT) return;
  float v = 0.0f;
  if (idx < WIN) {                        // W_in: [32][64] -> frag order, 4 ntiles
    int nt = idx >> 9; int r = idx & 511; int l = r >> 3; int j = r & 7;
    int n = nt*16 + (l & 15);
    int k = (l >> 4)*8 + j;
    v = W_in[k*64 + n];
  } else {
    int e2   = idx - WIN;
    int pair = (e2 >= WA + WB) ? 1 : 0;
    int e    = e2 - pair * (WA + WB);
    if (e < WA) {                         // a-type: I=64, O=129 (9 ntiles)
      const float* coef = pair ? c1a : c0a;
      const float* sb   = pair ? sb1a : sb0a;
      const float* ss   = pair ? ss1a : ss0a;
      int ks = e / 4608; int r = e - ks*4608;
      int nt = r >> 9;   int q = r & 511;
      int l  = q >> 3;   int j = q & 7;
      int n  = nt*16 + (l & 15);
      int k  = ks*32 + (l >> 4)*8 + j;
      if (n < 129) {
        if (k < 512) { int i = k >> 3, p = k & 7; v = ss[i*129+n] * coef[(i*129+n)*8 + p]; }
        else         { int i = k - 512;           v = sb[i*129+n]; }     // i < 64
      }
    } else {                              // b-type: I=129, O=64 (4 ntiles)
      const float* coef = pair ? c1b : c0b;
      const float* sb   = pair ? sb1b : sb0b;
      const float* ss   = pair ? ss1b : ss0b;
      int eb = e - WA;
      int ks = eb >> 11; int r = eb & 2047;
      int nt = r >> 9;   int q = r & 511;
      int l  = q >> 3;   int j = q & 7;
      int n  = nt*16 + (l & 15);
      int k  = ks*32 + (l >> 4)*8 + j;
      if (k < 1088) { int i = k >> 3, p = k & 7; if (i < 129) v = ss[i*64+n] * coef[(i*64+n)*8 + p]; }
      else          { int i = k - 1088;          if (i < 129) v = sb[i*64+n]; }
    }
  }
  wt[idx] = (_Float16)v;
}

// ---------------------------------------------------------------------------
// feat8: 8 B-spline basis values of x as a ready A-fragment (half8).
// Same math/placement as r5 (validated, absmax 0.0059); packing via
// cvt_pkrtz (1 inst per f32-pair) instead of four 16-bit inserts.
// ---------------------------------------------------------------------------
__device__ __forceinline__ half8 feat8(float x) {
  float s  = (x + 2.2f) * 2.5f;
  float mf = floorf(s);
  int   m  = (int)mf;
  float u  = s - mf;
  float t  = 1.0f - u;
  float u2 = u*u;
  float w0 = t*t*t * (1.0f/6.0f);
  float w3 = u2*u * (1.0f/6.0f);
  float w1 = fmaf(u2, fmaf(0.5f, u, -1.0f), 2.0f/3.0f);   // (3u^3-6u^2+4)/6
  float w2 = 1.0f - w0 - w1 - w3;                          // partition of unity
  union { fp16x2 h2[2]; uint64_t u64; } P;
  P.h2[0] = __builtin_amdgcn_cvt_pkrtz(w0, w1);
  P.h2[1] = __builtin_amdgcn_cvt_pkrtz(w2, w3);
  uint64_t w01 = (m >= 0 && m <= 10) ? P.u64 : 0ull;
  int sh = (m - 3) * 16;                                   // bits; [-48,112] valid
  uint64_t q0 = (sh >= 0) ? ((sh < 64) ? (w01 << sh) : 0ull) : (w01 >> (-sh));
  uint64_t q1 = (sh >= 64) ? (w01 << (sh - 64))
                           : ((sh > 0) ? (w01 >> (64 - sh)) : 0ull);
  union { uint64_t q[2]; half8 h; } R;
  R.q[0] = q0; R.q[1] = q1;
  return R.h;
}

// ---------------------------------------------------------------------------
// one KAN layer, per-wave (16 rows = 1 m-tile), register A-frags (r5).
// New: bp[] lane-constant B addressing; alignment __syncthreads to keep the
// block's 4 waves' identical B-streams overlapped in L1 (no data dependency —
// per-wave states are private, so barriers cannot affect correctness).
// ---------------------------------------------------------------------------
template<int KSPL, int KSIL, int NT, int SIN, int O, int SOUT>
__device__ __forceinline__ void kan_layer(
    const _Float16* __restrict__ hinw, _Float16* __restrict__ houtw,
    const _Float16* __restrict__ wt, const float* __restrict__ bias, int lane) {
  const int ln = lane & 15;
  const int kq = lane >> 4;
  const half8* __restrict__ bp = (const half8*)wt + lane;   // +lane*16B, loop-invariant
  floatx4 acc[NT];
  #pragma unroll
  for (int j = 0; j < NT; ++j) acc[j] = (floatx4){0.f, 0.f, 0.f, 0.f};

  // ---- spline k-steps: input i = ks*4 + kq ----
  #pragma unroll 2
  for (int ks = 0; ks < KSPL; ++ks) {
    if ((ks & 7) == 0) __syncthreads();                    // alignment only
    float xv = (float)hinw[ln*SIN + ks*4 + kq];
    half8 A = feat8(xv);
    #pragma unroll
    for (int j = 0; j < NT; ++j) {
      half8 B = bp[(ks*NT + j)*64];
      acc[j] = __builtin_amdgcn_mfma_f32_16x16x32_f16(A, B, acc[j], 0, 0, 0);
    }
  }

  __syncthreads();                                         // alignment only
  // ---- silu k-steps: slots = silu(h[ln][sk*32+kq*8 .. +7]) ----
  #pragma unroll 2
  for (int sk = 0; sk < KSIL; ++sk) {
    half8 h8 = *(const half8*)&hinw[ln*SIN + sk*32 + kq*8];
    union { fp16x2 h2[4]; half8 h8; } A;
    #pragma unroll
    for (int e = 0; e < 4; ++e) {
      float x0 = (float)h8[2*e], x1 = (float)h8[2*e + 1];
      float s0 = x0 / (1.0f + __expf(-x0));
      float s1 = x1 / (1.0f + __expf(-x1));
      A.h2[e] = __builtin_amdgcn_cvt_pkrtz(s0, s1);
    }
    #pragma unroll
    for (int j = 0; j < NT; ++j) {
      half8 B = bp[((KSPL + sk)*NT + j)*64];
      acc[j] = __builtin_amdgcn_mfma_f32_16x16x32_f16(A.h8, B, acc[j], 0, 0, 0);
    }
  }

  // ---- epilogue: C/D col=lane&15, row=kq*4+r (m89-verified) ----
  #pragma unroll
  for (int j = 0; j < NT; ++j) {
    int col = j*16 + ln;
    if (col < O) {
      float bv = bias[col];
      #pragma unroll
      for (int r = 0; r < 4; ++r)
        houtw[(kq*4 + r)*SOUT + col] = (_Float16)(acc[j][r] + bv);
    }
  }
}

// ---------------------------------------------------------------------------
// fused forward. r5 occupancy: LDS 25856 B, __launch_bounds__(256,4)
// -> 4 blocks/CU = 16 waves/CU; grid 1024 = exactly 4 blocks/CU.
// ---------------------------------------------------------------------------
extern "C" __global__ void __launch_bounds__(256, 4)
kan_forward(const float* __restrict__ x, const float* __restrict__ b_in,
            const float* __restrict__ W_out, const _Float16* __restrict__ wt,
            const float* __restrict__ bias0a, const float* __restrict__ bias0b,
            const float* __restrict__ bias1a, const float* __restrict__ bias1b,
            float* __restrict__ out) {
  __shared__ _Float16 hM[4][HM_SLICE];
  __shared__ _Float16 hH[4][16*SH];
  const int t    = threadIdx.x;
  const int wv   = t >> 6;
  const int lane = t & 63;
  const int ln   = lane & 15;
  const int kq   = lane >> 4;
  _Float16* hMw = hM[wv];
  _Float16* hHw = hH[wv];
  const int rbase = blockIdx.x * TB + wv * 16;

  // zero hM spots padded reads can touch: col 129 each row + tail pad
  hMw[16*SM + lane] = (_Float16)0.0f;
  if (lane < 16) hMw[lane*SM + 129] = (_Float16)0.0f;

  // stage 1: hH = relu(x @ W_in + b_in). A-frag straight from global x.
  {
    const float* xr = &x[(rbase + ln)*32 + kq*8];
    float4 v0 = *(const float4*)&xr[0];
    float4 v1 = *(const float4*)&xr[4];
    union { fp16x2 h2[4]; half8 h8; } A;
    A.h2[0] = __builtin_amdgcn_cvt_pkrtz(v0.x, v0.y);
    A.h2[1] = __builtin_amdgcn_cvt_pkrtz(v0.z, v0.w);
    A.h2[2] = __builtin_amdgcn_cvt_pkrtz(v1.x, v1.y);
    A.h2[3] = __builtin_amdgcn_cvt_pkrtz(v1.z, v1.w);
    const half8* bp = (const half8*)wt + lane;
    #pragma unroll
    for (int nt = 0; nt < 4; ++nt) {
      floatx4 z = (floatx4){0.f, 0.f, 0.f, 0.f};
      half8 B = bp[nt*64];
      floatx4 a = __builtin_amdgcn_mfma_f32_16x16x32_f16(A.h8, B, z, 0, 0, 0);
      int col = nt*16 + ln;
      float bv = b_in[col];
      #pragma unroll
      for (int r = 0; r < 4; ++r)
        hHw[(kq*4 + r)*SH + col] = (_Float16)fmaxf(a[r] + bv, 0.0f);
    }
  }

  kan_layer<16,2,9,SH,129,SM>(hHw, hMw, wt + WIN,             bias0a, lane);
  kan_layer<34,5,4,SM, 64,SH>(hMw, hHw, wt + WIN + WA,        bias0b, lane);
  kan_layer<16,2,9,SH,129,SM>(hHw, hMw, wt + WIN + WA + WB,   bias1a, lane);
  kan_layer<34,5,4,SM, 64,SH>(hMw, hHw, wt + WIN + 2*WA + WB, bias1b, lane);

  // final: out = sigmoid(hH @ W_out); kq-partials reduced by shuffle
  {
    float s = 0.0f;
    #pragma unroll
    for (int j = 0; j < 16; ++j)
      s = fmaf((float)hHw[ln*SH + kq*16 + j], W_out[kq*16 + j], s);
    s += __shfl_down(s, 32);
    s += __shfl_down(s, 16);
    if (lane < 16) out[rbase + ln] = 1.0f / (1.0f + __expf(-s));
  }
}

// ---------------------------------------------------------------------------
extern "C" void kernel_launch(void* const* d_in, const int* in_sizes, int n_in,
                              void* d_out, int out_size, void* d_ws, size_t ws_size,
                              hipStream_t stream) {
  const float* x     = (const float*)d_in[0];
  const float* W_in  = (const float*)d_in[1];
  const float* b_in  = (const float*)d_in[2];
  const float* W_out = (const float*)d_in[3];
  const float* c0a = (const float*)d_in[4];  const float* sb0a = (const float*)d_in[5];
  const float* ss0a= (const float*)d_in[6];  const float* bias0a=(const float*)d_in[7];
  const float* c0b = (const float*)d_in[8];  const float* sb0b = (const float*)d_in[9];
  const float* ss0b= (const float*)d_in[10]; const float* bias0b=(const float*)d_in[11];
  const float* c1a = (const float*)d_in[12]; const float* sb1a = (const float*)d_in[13];
  const float* ss1a= (const float*)d_in[14]; const float* bias1a=(const float*)d_in[15];
  const float* c1b = (const float*)d_in[16]; const float* sb1b = (const float*)d_in[17];
  const float* ss1b= (const float*)d_in[18]; const float* bias1b=(const float*)d_in[19];
  float*    out = (float*)d_out;
  _Float16* wt  = (_Float16*)d_ws;       // 655,360 B scratch, repacked every call

  setup_weights<<<(WTOT + 255)/256, 256, 0, stream>>>(
      W_in, c0a, sb0a, ss0a, c0b, sb0b, ss0b,
      c1a, sb1a, ss1a, c1b, sb1b, ss1b, wt);

  kan_forward<<<BATCH/TB, 256, 0, stream>>>(
      x, b_in, W_out, wt, bias0a, bias0b, bias1a, bias1b, out);
}

// Round 9
// 176.677 us; speedup vs baseline: 1.1961x; 1.0641x over previous
//
#include <hip/hip_runtime.h>
#include <math.h>
#include <stdint.h>

// ---------------- model constants ----------------
#define BATCH 65536
#define TB 64            // 4 waves x 16 rows, each wave independent (r5 structure)

typedef __fp16   fp16x2 __attribute__((ext_vector_type(2)));   // cvt_pkrtz result type
typedef _Float16 half8  __attribute__((ext_vector_type(8)));
typedef float   floatx4 __attribute__((ext_vector_type(4)));

// per-wave LDS strides (halves)
#define SH 68            // hH: 64 cols + 4 pad  (34 dwords ≡ 2 mod 32: conflict-free)
#define SM 130           // hM: 129 cols + 1     (65 dwords ≡ 1 mod 32: conflict-free)
#define HM_SLICE (16*SM + 64)   // +64 halves zeroed tail pad (overrun reads)

// packed-weight geometry (f16), FRAGMENT-ORDERED (identical to r5/r8):
//   element (ks, nt, lane, j) at ((ks*NT + nt)*512) + lane*8 + j
//   maps to B[k = ks*32 + (lane>>4)*8 + j][n = nt*16 + (lane&15)]
#define WIN 2048          // stage1: 1 kstep x 4 ntiles x 512
#define KSA 18            // a: 16 spline ksteps (512 k) + 2 silu (64)
#define KSB 39            // b: 34 spline ksteps (1088 k, 129 real) + 5 silu (160, 129 real)
#define WA (KSA*9*512)    // 82944
#define WB (KSB*4*512)    // 79872
#define WTOT (WIN + 2*(WA+WB))   // 327680 halfs = 655360 B of d_ws

// ---------------------------------------------------------------------------
// setup: pack all weights f16 in fragment order (identical to r5/r8).
// ---------------------------------------------------------------------------
__global__ void setup_weights(
    const float* __restrict__ W_in,
    const float* __restrict__ c0a, const float* __restrict__ sb0a, const float* __restrict__ ss0a,
    const float* __restrict__ c0b, const float* __restrict__ sb0b, const float* __restrict__ ss0b,
    const float* __restrict__ c1a, const float* __restrict__ sb1a, const float* __restrict__ ss1a,
    const float* __restrict__ c1b, const float* __restrict__ sb1b, const float* __restrict__ ss1b,
    _Float16* __restrict__ wt) {
  int idx = blockIdx.x * 256 + threadIdx.x;
  if (idx >= WTOT) return;
  float v = 0.0f;
  if (idx < WIN) {                        // W_in: [32][64] -> frag order, 4 ntiles
    int nt = idx >> 9; int r = idx & 511; int l = r >> 3; int j = r & 7;
    int n = nt*16 + (l & 15);
    int k = (l >> 4)*8 + j;
    v = W_in[k*64 + n];
  } else {
    int e2   = idx - WIN;
    int pair = (e2 >= WA + WB) ? 1 : 0;
    int e    = e2 - pair * (WA + WB);
    if (e < WA) {                         // a-type: I=64, O=129 (9 ntiles)
      const float* coef = pair ? c1a : c0a;
      const float* sb   = pair ? sb1a : sb0a;
      const float* ss   = pair ? ss1a : ss0a;
      int ks = e / 4608; int r = e - ks*4608;
      int nt = r >> 9;   int q = r & 511;
      int l  = q >> 3;   int j = q & 7;
      int n  = nt*16 + (l & 15);
      int k  = ks*32 + (l >> 4)*8 + j;
      if (n < 129) {
        if (k < 512) { int i = k >> 3, p = k & 7; v = ss[i*129+n] * coef[(i*129+n)*8 + p]; }
        else         { int i = k - 512;           v = sb[i*129+n]; }     // i < 64
      }
    } else {                              // b-type: I=129, O=64 (4 ntiles)
      const float* coef = pair ? c1b : c0b;
      const float* sb   = pair ? sb1b : sb0b;
      const float* ss   = pair ? ss1b : ss0b;
      int eb = e - WA;
      int ks = eb >> 11; int r = eb & 2047;
      int nt = r >> 9;   int q = r & 511;
      int l  = q >> 3;   int j = q & 7;
      int n  = nt*16 + (l & 15);
      int k  = ks*32 + (l >> 4)*8 + j;
      if (k < 1088) { int i = k >> 3, p = k & 7; if (i < 129) v = ss[i*64+n] * coef[(i*64+n)*8 + p]; }
      else          { int i = k - 1088;          if (i < 129) v = sb[i*64+n]; }
    }
  }
  wt[idx] = (_Float16)v;
}

// ---------------------------------------------------------------------------
// feat8: 8 B-spline basis values of x as a ready A-fragment (half8).
// Funnel-shift placement + cvt_pkrtz packing (validated r8, absmax 0.0078).
// ---------------------------------------------------------------------------
__device__ __forceinline__ half8 feat8(float x) {
  float s  = (x + 2.2f) * 2.5f;
  float mf = floorf(s);
  int   m  = (int)mf;
  float u  = s - mf;
  float t  = 1.0f - u;
  float u2 = u*u;
  float w0 = t*t*t * (1.0f/6.0f);
  float w3 = u2*u * (1.0f/6.0f);
  float w1 = fmaf(u2, fmaf(0.5f, u, -1.0f), 2.0f/3.0f);   // (3u^3-6u^2+4)/6
  float w2 = 1.0f - w0 - w1 - w3;                          // partition of unity
  union { fp16x2 h2[2]; uint64_t u64; } P;
  P.h2[0] = __builtin_amdgcn_cvt_pkrtz(w0, w1);
  P.h2[1] = __builtin_amdgcn_cvt_pkrtz(w2, w3);
  uint64_t w01 = (m >= 0 && m <= 10) ? P.u64 : 0ull;
  int sh = (m - 3) * 16;                                   // bits; [-48,112] valid
  uint64_t q0 = (sh >= 0) ? ((sh < 64) ? (w01 << sh) : 0ull) : (w01 >> (-sh));
  uint64_t q1 = (sh >= 64) ? (w01 << (sh - 64))
                           : ((sh > 0) ? (w01 >> (64 - sh)) : 0ull);
  union { uint64_t q[2]; half8 h; } R;
  R.q[0] = q0; R.q[1] = q1;
  return R.h;
}

// ---------------------------------------------------------------------------
// one KAN layer, per-wave (16 rows = 1 m-tile), register A-frags.
// NEW (r9): merged spline+silu k-loop with explicit register double-buffer
// prefetch of the first PF B-tiles one k-step ahead (weights are k-contiguous
// so prefetch flows across the spline->silu boundary). No barriers at all.
// PF=4 for NT=9 (VGPR budget), PF=NT for NT=4. unroll 2 -> SSA renames the
// Bcur=Bpre copies away.
// ---------------------------------------------------------------------------
template<int KSPL, int KSIL, int NT, int SIN, int O, int SOUT>
__device__ __forceinline__ void kan_layer(
    const _Float16* __restrict__ hinw, _Float16* __restrict__ houtw,
    const _Float16* __restrict__ wt, const float* __restrict__ bias, int lane) {
  constexpr int KTOT = KSPL + KSIL;
  constexpr int PF   = (NT > 4) ? 4 : NT;
  const int ln = lane & 15;
  const int kq = lane >> 4;
  const half8* __restrict__ bp = (const half8*)wt + lane;   // +lane*16B, loop-invariant
  floatx4 acc[NT];
  #pragma unroll
  for (int j = 0; j < NT; ++j) acc[j] = (floatx4){0.f, 0.f, 0.f, 0.f};

  half8 Bpre[PF];
  #pragma unroll
  for (int j = 0; j < PF; ++j) Bpre[j] = bp[j*64];          // preload ks=0

  #pragma unroll 2
  for (int ks = 0; ks < KTOT; ++ks) {
    // ---- A-fragment in registers ----
    half8 A;
    if (ks < KSPL) {                       // spline: input i = ks*4 + kq
      float xv = (float)hinw[ln*SIN + ks*4 + kq];
      A = feat8(xv);
    } else {                               // silu: slots sk*32+kq*8 ..
      int sk = ks - KSPL;
      half8 h8 = *(const half8*)&hinw[ln*SIN + sk*32 + kq*8];
      union { fp16x2 h2[4]; half8 v; } Au;
      #pragma unroll
      for (int e = 0; e < 4; ++e) {
        float x0 = (float)h8[2*e], x1 = (float)h8[2*e + 1];
        float s0 = x0 / (1.0f + __expf(-x0));
        float s1 = x1 / (1.0f + __expf(-x1));
        Au.h2[e] = __builtin_amdgcn_cvt_pkrtz(s0, s1);
      }
      A = Au.v;
    }
    // ---- rotate prefetch buffer, issue next prefetch ----
    half8 Bcur[PF];
    #pragma unroll
    for (int j = 0; j < PF; ++j) Bcur[j] = Bpre[j];
    const int nks = (ks + 1 < KTOT) ? (ks + 1) : ks;   // clamp: no OOB past layer
    #pragma unroll
    for (int j = 0; j < PF; ++j) Bpre[j] = bp[(nks*NT + j)*64];
    // ---- MFMAs: prefetched tiles, then in-iteration tail tiles ----
    #pragma unroll
    for (int j = 0; j < PF; ++j)
      acc[j] = __builtin_amdgcn_mfma_f32_16x16x32_f16(A, Bcur[j], acc[j], 0, 0, 0);
    #pragma unroll
    for (int j = PF; j < NT; ++j) {
      half8 B = bp[(ks*NT + j)*64];
      acc[j] = __builtin_amdgcn_mfma_f32_16x16x32_f16(A, B, acc[j], 0, 0, 0);
    }
  }

  // ---- epilogue: C/D col=lane&15, row=kq*4+r (m89-verified) ----
  #pragma unroll
  for (int j = 0; j < NT; ++j) {
    int col = j*16 + ln;
    if (col < O) {
      float bv = bias[col];
      #pragma unroll
      for (int r = 0; r < 4; ++r)
        houtw[(kq*4 + r)*SOUT + col] = (_Float16)(acc[j][r] + bv);
    }
  }
}

// ---------------------------------------------------------------------------
// fused forward, zero __syncthreads. LDS 25856 B, __launch_bounds__(256,4)
// -> 4 blocks/CU = 16 waves/CU; grid 1024 = exactly 4 blocks/CU.
// ---------------------------------------------------------------------------
extern "C" __global__ void __launch_bounds__(256, 4)
kan_forward(const float* __restrict__ x, const float* __restrict__ b_in,
            const float* __restrict__ W_out, const _Float16* __restrict__ wt,
            const float* __restrict__ bias0a, const float* __restrict__ bias0b,
            const float* __restrict__ bias1a, const float* __restrict__ bias1b,
            float* __restrict__ out) {
  __shared__ _Float16 hM[4][HM_SLICE];
  __shared__ _Float16 hH[4][16*SH];
  const int t    = threadIdx.x;
  const int wv   = t >> 6;
  const int lane = t & 63;
  const int ln   = lane & 15;
  const int kq   = lane >> 4;
  _Float16* hMw = hM[wv];
  _Float16* hHw = hH[wv];
  const int rbase = blockIdx.x * TB + wv * 16;

  // zero hM spots padded reads can touch: col 129 each row + tail pad
  hMw[16*SM + lane] = (_Float16)0.0f;
  if (lane < 16) hMw[lane*SM + 129] = (_Float16)0.0f;

  // stage 1: hH = relu(x @ W_in + b_in). A-frag straight from global x.
  {
    const float* xr = &x[(rbase + ln)*32 + kq*8];
    float4 v0 = *(const float4*)&xr[0];
    float4 v1 = *(const float4*)&xr[4];
    union { fp16x2 h2[4]; half8 h8; } A;
    A.h2[0] = __builtin_amdgcn_cvt_pkrtz(v0.x, v0.y);
    A.h2[1] = __builtin_amdgcn_cvt_pkrtz(v0.z, v0.w);
    A.h2[2] = __builtin_amdgcn_cvt_pkrtz(v1.x, v1.y);
    A.h2[3] = __builtin_amdgcn_cvt_pkrtz(v1.z, v1.w);
    const half8* bp = (const half8*)wt + lane;
    #pragma unroll
    for (int nt = 0; nt < 4; ++nt) {
      floatx4 z = (floatx4){0.f, 0.f, 0.f, 0.f};
      half8 B = bp[nt*64];
      floatx4 a = __builtin_amdgcn_mfma_f32_16x16x32_f16(A.h8, B, z, 0, 0, 0);
      int col = nt*16 + ln;
      float bv = b_in[col];
      #pragma unroll
      for (int r = 0; r < 4; ++r)
        hHw[(kq*4 + r)*SH + col] = (_Float16)fmaxf(a[r] + bv, 0.0f);
    }
  }

  kan_layer<16,2,9,SH,129,SM>(hHw, hMw, wt + WIN,             bias0a, lane);
  kan_layer<34,5,4,SM, 64,SH>(hMw, hHw, wt + WIN + WA,        bias0b, lane);
  kan_layer<16,2,9,SH,129,SM>(hHw, hMw, wt + WIN + WA + WB,   bias1a, lane);
  kan_layer<34,5,4,SM, 64,SH>(hMw, hHw, wt + WIN + 2*WA + WB, bias1b, lane);

  // final: out = sigmoid(hH @ W_out); kq-partials reduced by shuffle
  {
    float s = 0.0f;
    #pragma unroll
    for (int j = 0; j < 16; ++j)
      s = fmaf((float)hHw[ln*SH + kq*16 + j], W_out[kq*16 + j], s);
    s += __shfl_down(s, 32);
    s += __shfl_down(s, 16);
    if (lane < 16) out[rbase + ln] = 1.0f / (1.0f + __expf(-s));
  }
}

// ---------------------------------------------------------------------------
extern "C" void kernel_launch(void* const* d_in, const int* in_sizes, int n_in,
                              void* d_out, int out_size, void* d_ws, size_t ws_size,
                              hipStream_t stream) {
  const float* x     = (const float*)d_in[0];
  const float* W_in  = (const float*)d_in[1];
  const float* b_in  = (const float*)d_in[2];
  const float* W_out = (const float*)d_in[3];
  const float* c0a = (const float*)d_in[4];  const float* sb0a = (const float*)d_in[5];
  const float* ss0a= (const float*)d_in[6];  const float* bias0a=(const float*)d_in[7];
  const float* c0b = (const float*)d_in[8];  const float* sb0b = (const float*)d_in[9];
  const float* ss0b= (const float*)d_in[10]; const float* bias0b=(const float*)d_in[11];
  const float* c1a = (const float*)d_in[12]; const float* sb1a = (const float*)d_in[13];
  const float* ss1a= (const float*)d_in[14]; const float* bias1a=(const float*)d_in[15];
  const float* c1b = (const float*)d_in[16]; const float* sb1b = (const float*)d_in[17];
  const float* ss1b= (const float*)d_in[18]; const float* bias1b=(const float*)d_in[19];
  float*    out = (float*)d_out;
  _Float16* wt  = (_Float16*)d_ws;       // 655,360 B scratch, repacked every call

  setup_weights<<<(WTOT + 255)/256, 256, 0, stream>>>(
      W_in, c0a, sb0a, ss0a, c0b, sb0b, ss0b,
      c1a, sb1a, ss1a, c1b, sb1b, ss1b, wt);

  kan_forward<<<BATCH/TB, 256, 0, stream>>>(
      x, b_in, W_out, wt, bias0a, bias0b, bias1a, bias1b, out);
}

// Round 10
// 170.120 us; speedup vs baseline: 1.2422x; 1.0385x over previous
//
#include <hip/hip_runtime.h>
#include <math.h>
#include <stdint.h>

// ---------------- model constants ----------------
#define BATCH 65536
#define TB 128           // 4 waves x 32 rows (one 32x32 m-tile each), independent

typedef __fp16   fp16x2  __attribute__((ext_vector_type(2)));   // cvt_pkrtz result
typedef _Float16 half8   __attribute__((ext_vector_type(8)));
typedef float    floatx16 __attribute__((ext_vector_type(16)));

// per-wave LDS strides (halves)
#define SH 68            // hH: 64 cols + 4 pad  (34 dwords ≡ 2 mod 32: conflict-free)
#define SM 130           // hM: 129 cols + 1     (65 dwords ≡ 1 mod 32)
#define HM_SLICE (32*SM + 64)   // +64 zeroed tail halves (silu b128 overrun, row 31)

// packed-weight geometry (f16), FRAGMENT-ORDERED for 32x32x16:
//   element (ks, nt, lane, j) at ((ks*NT + nt)*512) + lane*8 + j
//   maps to B[k = ks*16 + (lane>>5)*8 + j][n = nt*32 + (lane&31)]
// -> wave's B-frag load = base + lane*16B: one coalesced 1KB transaction.
#define WIN 2048          // stage1: 2 ksteps x 2 ntiles x 512
#define KSA 36            // a: 32 spline ksteps (512 k) + 4 silu (64)
#define KSB 74            // b: 65 spline ksteps (k<1040; 1032 real) + 9 silu (144, 129 real)
#define WA (KSA*5*512)    // 92160  (O=129 -> 5 n-tiles of 32)
#define WB (KSB*2*512)    // 75776  (O=64  -> 2 n-tiles)
#define WTOT (WIN + 2*(WA+WB))   // 337920 halfs = 675840 B of d_ws

// ---------------------------------------------------------------------------
// setup: pack all weights f16 in 32x32-fragment order.
// spline slot k=8i+p -> ss*coef; silu -> sb; zero outside real I/O.
// ---------------------------------------------------------------------------
__global__ void setup_weights(
    const float* __restrict__ W_in,
    const float* __restrict__ c0a, const float* __restrict__ sb0a, const float* __restrict__ ss0a,
    const float* __restrict__ c0b, const float* __restrict__ sb0b, const float* __restrict__ ss0b,
    const float* __restrict__ c1a, const float* __restrict__ sb1a, const float* __restrict__ ss1a,
    const float* __restrict__ c1b, const float* __restrict__ sb1b, const float* __restrict__ ss1b,
    _Float16* __restrict__ wt) {
  int idx = blockIdx.x * 256 + threadIdx.x;
  if (idx >= WTOT) return;
  float v = 0.0f;
  if (idx < WIN) {                        // W_in [32][64]: (ks*2+nt)*512 order
    int ks = idx >> 10; int nt = (idx >> 9) & 1;
    int q = idx & 511;  int l = q >> 3;   int j = q & 7;
    int n = nt*32 + (l & 31);
    int k = ks*16 + (l >> 5)*8 + j;
    v = W_in[k*64 + n];
  } else {
    int e2   = idx - WIN;
    int pair = (e2 >= WA + WB) ? 1 : 0;
    int e    = e2 - pair * (WA + WB);
    if (e < WA) {                         // a-type: I=64, O=129 (5 n-tiles)
      const float* coef = pair ? c1a : c0a;
      const float* sb   = pair ? sb1a : sb0a;
      const float* ss   = pair ? ss1a : ss0a;
      int ks = e / 2560; int r = e - ks*2560;
      int nt = r >> 9;   int q = r & 511;
      int l  = q >> 3;   int j = q & 7;
      int n  = nt*32 + (l & 31);
      int k  = ks*16 + (l >> 5)*8 + j;    // k < 576
      if (n < 129) {
        if (k < 512) { int i = k >> 3, p = k & 7; v = ss[i*129+n] * coef[(i*129+n)*8 + p]; }
        else         { int i = k - 512;           v = sb[i*129+n]; }     // i < 64
      }
    } else {                              // b-type: I=129, O=64 (2 n-tiles)
      const float* coef = pair ? c1b : c0b;
      const float* sb   = pair ? sb1b : sb0b;
      const float* ss   = pair ? ss1b : ss0b;
      int eb = e - WA;
      int ks = eb >> 10; int r = eb & 1023;
      int nt = r >> 9;   int q = r & 511;
      int l  = q >> 3;   int j = q & 7;
      int n  = nt*32 + (l & 31);
      int k  = ks*16 + (l >> 5)*8 + j;    // k < 1184
      if (k < 1032)      { int i = k >> 3, p = k & 7; v = ss[i*64+n] * coef[(i*64+n)*8 + p]; }
      else if (k >= 1040){ int s = k - 1040; if (s < 129) v = sb[s*64+n]; }
      // k in [1032,1040): dead pad slots -> 0
    }
  }
  wt[idx] = (_Float16)v;
}

// ---------------------------------------------------------------------------
// feat8: 8 B-spline basis values of x as a ready A-fragment half (8 halfs).
// Funnel-shift placement + cvt_pkrtz packing (validated r8/r9, absmax 0.0078).
// ---------------------------------------------------------------------------
__device__ __forceinline__ half8 feat8(float x) {
  float s  = (x + 2.2f) * 2.5f;
  float mf = floorf(s);
  int   m  = (int)mf;
  float u  = s - mf;
  float t  = 1.0f - u;
  float u2 = u*u;
  float w0 = t*t*t * (1.0f/6.0f);
  float w3 = u2*u * (1.0f/6.0f);
  float w1 = fmaf(u2, fmaf(0.5f, u, -1.0f), 2.0f/3.0f);   // (3u^3-6u^2+4)/6
  float w2 = 1.0f - w0 - w1 - w3;                          // partition of unity
  union { fp16x2 h2[2]; uint64_t u64; } P;
  P.h2[0] = __builtin_amdgcn_cvt_pkrtz(w0, w1);
  P.h2[1] = __builtin_amdgcn_cvt_pkrtz(w2, w3);
  uint64_t w01 = (m >= 0 && m <= 10) ? P.u64 : 0ull;
  int sh = (m - 3) * 16;                                   // bits; [-48,112] valid
  uint64_t q0 = (sh >= 0) ? ((sh < 64) ? (w01 << sh) : 0ull) : (w01 >> (-sh));
  uint64_t q1 = (sh >= 64) ? (w01 << (sh - 64))
                           : ((sh > 0) ? (w01 >> (64 - sh)) : 0ull);
  union { uint64_t q[2]; half8 h; } R;
  R.q[0] = q0; R.q[1] = q1;
  return R.h;
}

// ---------------------------------------------------------------------------
// one KAN layer, per-wave 32 rows = one 32x32 m-tile. A-frags in registers:
// spline k-step ks -> lane computes feat8 of input i=2ks+(lane>>5), row lane&31
// (A layout m=lane&31, k=(lane>>5)*8+j). Depth-2 register prefetch of B.
// ---------------------------------------------------------------------------
template<int KSPL, int KSIL, int NT, int SIN, int O, int SOUT>
__device__ __forceinline__ void kan_layer(
    const _Float16* __restrict__ hinw, _Float16* __restrict__ houtw,
    const _Float16* __restrict__ wt, const float* __restrict__ bias, int lane) {
  constexpr int KTOT = KSPL + KSIL;
  const int ln = lane & 31;
  const int kh = lane >> 5;
  const half8* __restrict__ bp = (const half8*)wt + lane;   // +lane*16B
  floatx16 acc[NT];
  #pragma unroll
  for (int j = 0; j < NT; ++j)
    #pragma unroll
    for (int e = 0; e < 16; ++e) acc[j][e] = 0.0f;

  half8 B0[NT], B1[NT];                       // depth-2 prefetch pipeline
  #pragma unroll
  for (int j = 0; j < NT; ++j) B0[j] = bp[j*64];
  #pragma unroll
  for (int j = 0; j < NT; ++j) B1[j] = bp[(NT + j)*64];

  #pragma unroll 2
  for (int ks = 0; ks < KTOT; ++ks) {
    // ---- A-fragment in registers ----
    half8 A;
    if (ks < KSPL) {                          // spline: input i = 2ks + kh
      float xv = (float)hinw[ln*SIN + 2*ks + kh];
      A = feat8(xv);
    } else {                                  // silu: slots sk*16 + kh*8 ..
      int sk = ks - KSPL;
      half8 h8 = *(const half8*)&hinw[ln*SIN + sk*16 + kh*8];
      union { fp16x2 h2[4]; half8 v; } Au;
      #pragma unroll
      for (int e = 0; e < 4; ++e) {
        float x0 = (float)h8[2*e], x1 = (float)h8[2*e + 1];
        float s0 = x0 / (1.0f + __expf(-x0));
        float s1 = x1 / (1.0f + __expf(-x1));
        Au.h2[e] = __builtin_amdgcn_cvt_pkrtz(s0, s1);
      }
      A = Au.v;
    }
    // ---- rotate prefetch, issue ks+2 ----
    half8 Bcur[NT];
    #pragma unroll
    for (int j = 0; j < NT; ++j) { Bcur[j] = B0[j]; B0[j] = B1[j]; }
    const int nks = (ks + 2 < KTOT) ? (ks + 2) : (KTOT - 1);  // clamp, no OOB
    #pragma unroll
    for (int j = 0; j < NT; ++j) B1[j] = bp[(nks*NT + j)*64];
    // ---- MFMAs ----
    #pragma unroll
    for (int j = 0; j < NT; ++j)
      acc[j] = __builtin_amdgcn_mfma_f32_32x32x16_f16(A, Bcur[j], acc[j], 0, 0, 0);
  }

  // ---- epilogue: C/D col=lane&31, row=(reg&3)+8*(reg>>2)+4*(lane>>5) ----
  #pragma unroll
  for (int j = 0; j < NT; ++j) {
    int col = j*32 + ln;
    if (col < O) {
      float bv = bias[col];
      #pragma unroll
      for (int r = 0; r < 16; ++r) {
        int row = (r & 3) + 8*(r >> 2) + 4*kh;
        houtw[row*SOUT + col] = (_Float16)(acc[j][r] + bv);
      }
    }
  }
}

// ---------------------------------------------------------------------------
// fused forward, zero __syncthreads, 32x32 MFMA, depth-2 B prefetch.
// LDS = 4*(32*130+64 + 32*68)*2 = 51200 B -> 2 blocks/CU; grid 512 = exact.
// ---------------------------------------------------------------------------
extern "C" __global__ void __launch_bounds__(256, 2)
kan_forward(const float* __restrict__ x, const float* __restrict__ b_in,
            const float* __restrict__ W_out, const _Float16* __restrict__ wt,
            const float* __restrict__ bias0a, const float* __restrict__ bias0b,
            const float* __restrict__ bias1a, const float* __restrict__ bias1b,
            float* __restrict__ out) {
  __shared__ _Float16 hM[4][HM_SLICE];
  __shared__ _Float16 hH[4][32*SH];
  const int t    = threadIdx.x;
  const int wv   = t >> 6;
  const int lane = t & 63;
  const int ln   = lane & 31;
  const int kh   = lane >> 5;
  _Float16* hMw = hM[wv];
  _Float16* hHw = hH[wv];
  const int rbase = blockIdx.x * TB + wv * 32;

  // zero hM spots padded reads can touch: col 129 each row + tail pad
  hMw[32*SM + lane] = (_Float16)0.0f;
  if (lane < 32) hMw[lane*SM + 129] = (_Float16)0.0f;

  // stage 1: hH = relu(x @ W_in + b_in). Two k-steps, 2 n-tiles.
  {
    const float* xr = &x[(rbase + ln)*32 + kh*8];
    float4 v0 = *(const float4*)&xr[0];
    float4 v1 = *(const float4*)&xr[4];
    float4 v2 = *(const float4*)&xr[16];
    float4 v3 = *(const float4*)&xr[20];
    union { fp16x2 h2[4]; half8 h8; } A0, A1;
    A0.h2[0] = __builtin_amdgcn_cvt_pkrtz(v0.x, v0.y);
    A0.h2[1] = __builtin_amdgcn_cvt_pkrtz(v0.z, v0.w);
    A0.h2[2] = __builtin_amdgcn_cvt_pkrtz(v1.x, v1.y);
    A0.h2[3] = __builtin_amdgcn_cvt_pkrtz(v1.z, v1.w);
    A1.h2[0] = __builtin_amdgcn_cvt_pkrtz(v2.x, v2.y);
    A1.h2[1] = __builtin_amdgcn_cvt_pkrtz(v2.z, v2.w);
    A1.h2[2] = __builtin_amdgcn_cvt_pkrtz(v3.x, v3.y);
    A1.h2[3] = __builtin_amdgcn_cvt_pkrtz(v3.z, v3.w);
    const half8* bp = (const half8*)wt + lane;
    #pragma unroll
    for (int nt = 0; nt < 2; ++nt) {
      floatx16 a;
      #pragma unroll
      for (int e = 0; e < 16; ++e) a[e] = 0.0f;
      a = __builtin_amdgcn_mfma_f32_32x32x16_f16(A0.h8, bp[nt*64],       a, 0, 0, 0);
      a = __builtin_amdgcn_mfma_f32_32x32x16_f16(A1.h8, bp[(2 + nt)*64], a, 0, 0, 0);
      int col = nt*32 + ln;
      float bv = b_in[col];
      #pragma unroll
      for (int r = 0; r < 16; ++r) {
        int row = (r & 3) + 8*(r >> 2) + 4*kh;
        hHw[row*SH + col] = (_Float16)fmaxf(a[r] + bv, 0.0f);
      }
    }
  }

  kan_layer<32,4,5,SH,129,SM>(hHw, hMw, wt + WIN,             bias0a, lane);
  kan_layer<65,9,2,SM, 64,SH>(hMw, hHw, wt + WIN + WA,        bias0b, lane);
  kan_layer<32,4,5,SH,129,SM>(hHw, hMw, wt + WIN + WA + WB,   bias1a, lane);
  kan_layer<65,9,2,SM, 64,SH>(hMw, hHw, wt + WIN + 2*WA + WB, bias1b, lane);

  // final: out = sigmoid(hH @ W_out); two col-halves reduced by shuffle
  {
    float s = 0.0f;
    #pragma unroll
    for (int j = 0; j < 32; ++j)
      s = fmaf((float)hHw[ln*SH + kh*32 + j], W_out[kh*32 + j], s);
    s += __shfl_down(s, 32);
    if (lane < 32) out[rbase + ln] = 1.0f / (1.0f + __expf(-s));
  }
}

// ---------------------------------------------------------------------------
extern "C" void kernel_launch(void* const* d_in, const int* in_sizes, int n_in,
                              void* d_out, int out_size, void* d_ws, size_t ws_size,
                              hipStream_t stream) {
  const float* x     = (const float*)d_in[0];
  const float* W_in  = (const float*)d_in[1];
  const float* b_in  = (const float*)d_in[2];
  const float* W_out = (const float*)d_in[3];
  const float* c0a = (const float*)d_in[4];  const float* sb0a = (const float*)d_in[5];
  const float* ss0a= (const float*)d_in[6];  const float* bias0a=(const float*)d_in[7];
  const float* c0b = (const float*)d_in[8];  const float* sb0b = (const float*)d_in[9];
  const float* ss0b= (const float*)d_in[10]; const float* bias0b=(const float*)d_in[11];
  const float* c1a = (const float*)d_in[12]; const float* sb1a = (const float*)d_in[13];
  const float* ss1a= (const float*)d_in[14]; const float* bias1a=(const float*)d_in[15];
  const float* c1b = (const float*)d_in[16]; const float* sb1b = (const float*)d_in[17];
  const float* ss1b= (const float*)d_in[18]; const float* bias1b=(const float*)d_in[19];
  float*    out = (float*)d_out;
  _Float16* wt  = (_Float16*)d_ws;       // 675,840 B scratch, repacked every call

  setup_weights<<<(WTOT + 255)/256, 256, 0, stream>>>(
      W_in, c0a, sb0a, ss0a, c0b, sb0b, ss0b,
      c1a, sb1a, ss1a, c1b, sb1b, ss1b, wt);

  kan_forward<<<BATCH/TB, 256, 0, stream>>>(
      x, b_in, W_out, wt, bias0a, bias0b, bias1a, bias1b, out);
}